// Round 12
// baseline (79.710 us; speedup 1.0000x reference)
//
#include <hip/hip_runtime.h>
#include <math.h>

// CapsuleLayer dynamic routing, MI355X — R12: GEMM once + streaming passes.
// B=128, R=4096, IN=16, OUT=32, C=2, 3 routing iterations.
//
// Lessons R8-R11: coop/grid.sync == launch gaps (no win); register- or
// LDS-resident priors spill at any useful occupancy (rule #20 + VGPR caps).
// R12 keeps the proven R7 machinery but runs the expensive part ONCE:
//   pass0: R7 MFMA pass (stage+pack W in LDS, x-gather, mfma 16x16x32_f16)
//          + store packed-f16 priors to GLOBAL in fragment order (67 MB).
//   pass1/2: pure streaming — no LDS, no barriers, no MFMA: reload h8
//          fragments (coalesced 16B/lane), dot with vsum, exp, accumulate.
//   redv: unchanged proven reduction (squash, vsum update / final out).
// Logits stay linear in the running v-sum (no logit storage); it0 uniform.
// k-slot safety (HW-verified R6+): both mfma operands put i=4*(L>>4)+j in
// elements 0..3, zeros in 4..7. C/D layout (m89): col=lane&15, row=4g+reg.
// f16 priors precision proven R1-R4 (absmax 0.0039 vs threshold 0.0124).
#define CB    128
#define CR    4096
#define CIN   16
#define COUT  32
#define CCAP  2
#define RC    16            // r rows per chunk
#define NRCH  (CR / RC)     // 256 chunks per c
#define EPSF  1e-12f

typedef _Float16 h8  __attribute__((ext_vector_type(8)));
typedef _Float16 h4t __attribute__((ext_vector_type(4)));
typedef float    f4  __attribute__((ext_vector_type(4)));
typedef float    f8v __attribute__((ext_vector_type(8)));

// ---------------------------------------------------------------------------
// stage W rows [r0, r0+16) of capsule c -> packed f16 fragment order (16 KB)
// via 16 KB scratch, two 8-row halves. Startup only, proven R7-R11.
// ---------------------------------------------------------------------------
__device__ __forceinline__ void stage_pack_W(const float* __restrict__ w,
                                             int c, int r0, int t,
                                             _Float16* WpL, float* Stg)
{
  h4t* WpL4 = (h4t*)WpL;
#pragma unroll
  for (int h = 0; h < 2; ++h) {
    const float4* src = (const float4*)(w + ((size_t)c * CR + r0 + h * 8) * 512);
    ((float4*)Stg)[t]       = src[t];
    ((float4*)Stg)[t + 512] = src[t + 512];
    __syncthreads();
#pragma unroll
    for (int q = 0; q < 2; ++q) {
      const int sl  = t * 2 + q;         // 0..1023
      const int rr  = sl >> 7;           // row within half
      const int rem = sl & 127;          // ot*64 + L
      const int ot  = rem >> 6;
      const int gs  = (rem >> 4) & 3;
      const int ms  = rem & 15;
      h4t v;
#pragma unroll
      for (int j = 0; j < 4; ++j)
        v[j] = (_Float16)Stg[rr * 512 + (4 * gs + j) * 32 + ot * 16 + ms];
      WpL4[(h * 8 + rr) * 128 + rem] = v;
    }
    __syncthreads();
  }
}

// direct fragment-order partial stores (coalesced, no barriers). Proven.
__device__ __forceinline__ void store_partials(float* __restrict__ partialA,
                                               float* __restrict__ partialE,
                                               const float* accA, const float* accB,
                                               float esum, int c, int rch,
                                               int t, int g, int b)
{
  float4 a4 = {accA[0], accA[1], accA[2], accA[3]};
  float4 b4 = {accB[0], accB[1], accB[2], accB[3]};
  float* dst = partialA + ((size_t)(c * NRCH + rch)) * 4096 + (size_t)t * 8;
  *(float4*)dst = a4;
  *(float4*)(dst + 4) = b4;
  if (g == 0) partialE[((size_t)(c * NRCH + rch)) * CB + b] = esum;
}

// ---------------------------------------------------------------------------
// pass0: grid = C*NRCH = 512 blocks, 512 threads. R7 MFMA pass with uniform
// softmax (e=1) + packed-f16 priors stored to global in fragment order:
//   priors16[((c*NRCH+rch)*RC + ri)*512 + t] = {pA[0..3], pB[0..3]} as h8.
// ---------------------------------------------------------------------------
__global__ __launch_bounds__(512) void caps_pass0_kernel(
    const float* __restrict__ x, const float* __restrict__ w,
    h8* __restrict__ priors16,
    float* __restrict__ partialA, float* __restrict__ partialE)
{
  const int blk = (int)blockIdx.x;
  const int c = blk >> 8, rch = blk & 255;
  const int r0 = rch * RC;
  const int t = (int)threadIdx.x;
  const int wv = t >> 6, L = t & 63, g = L >> 4, m = L & 15;
  const int b  = wv * 16 + m;

  __shared__ __align__(16) char lds[32768];
  _Float16* WpL = (_Float16*)lds;          // [0,16384) packed frags
  float* Stg = (float*)(lds + 16384);      // [16384,32768) stage scratch

  stage_pack_W(w, c, r0, t, WpL, Stg);

  const h4t* WpL4 = (const h4t*)WpL;
  h8* prow = priors16 + ((size_t)(c * NRCH + rch)) * RC * 512 + t;

  float accA[4] = {0.f, 0.f, 0.f, 0.f};
  float accB[4] = {0.f, 0.f, 0.f, 0.f};

#pragma unroll 4
  for (int ri = 0; ri < RC; ++ri) {
    const int r = r0 + ri;
    // B-frag: x[b][r][4g..4g+3] -> elements 0..3, zeros 4..7
    float4 xf = *(const float4*)(x + ((size_t)b * CR + r) * CIN + 4 * g);
    h8 bx = {(_Float16)xf.x, (_Float16)xf.y, (_Float16)xf.z, (_Float16)xf.w,
             (_Float16)0.f, (_Float16)0.f, (_Float16)0.f, (_Float16)0.f};
    h4t wA4 = WpL4[ri * 128 + L];
    h4t wB4 = WpL4[ri * 128 + 64 + L];
    h8 aA = {wA4[0], wA4[1], wA4[2], wA4[3],
             (_Float16)0.f, (_Float16)0.f, (_Float16)0.f, (_Float16)0.f};
    h8 aB = {wB4[0], wB4[1], wB4[2], wB4[3],
             (_Float16)0.f, (_Float16)0.f, (_Float16)0.f, (_Float16)0.f};
    f4 z = {0.f, 0.f, 0.f, 0.f};
    f4 pA = __builtin_amdgcn_mfma_f32_16x16x32_f16(aA, bx, z, 0, 0, 0);
    f4 pB = __builtin_amdgcn_mfma_f32_16x16x32_f16(aB, bx, z, 0, 0, 0);

    // store packed priors (fire-and-forget dwordx4, coalesced across t)
    h8 pk = {(_Float16)pA[0], (_Float16)pA[1], (_Float16)pA[2], (_Float16)pA[3],
             (_Float16)pB[0], (_Float16)pB[1], (_Float16)pB[2], (_Float16)pB[3]};
    prow[ri * 512] = pk;

#pragma unroll
    for (int j = 0; j < 4; ++j) { accA[j] += pA[j]; accB[j] += pB[j]; }
  }
  store_partials(partialA, partialE, accA, accB, (float)RC, 0 * 0 + c, rch, t, g, b);
}

// ---------------------------------------------------------------------------
// passN: pure streaming iteration. grid = 512 blocks x 512 threads, NO LDS,
// no barriers, no MFMA. Thread t re-reads its own 16 h8 fragment records
// (16B/lane, contiguous 1 KB per wave per step), dot+exp+accumulate.
// ---------------------------------------------------------------------------
__global__ __launch_bounds__(512) void caps_passN_kernel(
    const h8* __restrict__ priors16, const float* __restrict__ vsum,
    float* __restrict__ partialA, float* __restrict__ partialE)
{
  const int blk = (int)blockIdx.x;
  const int c = blk >> 8, rch = blk & 255;
  const int t = (int)threadIdx.x;
  const int wv = t >> 6, L = t & 63, g = L >> 4, m = L & 15;
  const int b  = wv * 16 + m;

  const float* vb = vsum + ((size_t)c * CB + b) * COUT;
  float4 vA = *(const float4*)(vb + 4 * g);
  float4 vB = *(const float4*)(vb + 16 + 4 * g);

  const h8* prow = priors16 + ((size_t)(c * NRCH + rch)) * RC * 512 + t;

  float accA[4] = {0.f, 0.f, 0.f, 0.f};
  float accB[4] = {0.f, 0.f, 0.f, 0.f};
  float esum = 0.f;

#pragma unroll 4
  for (int ri = 0; ri < RC; ++ri) {
    f8v p = __builtin_convertvector(prow[ri * 512], f8v);
    float d = p[0] * vA.x + p[1] * vA.y + p[2] * vA.z + p[3] * vA.w
            + p[4] * vB.x + p[5] * vB.y + p[6] * vB.z + p[7] * vB.w;
    d += __shfl_xor(d, 16);
    d += __shfl_xor(d, 32);
    const float e = __expf(d);   // safe: |d| <= ||p_row|| * ||vsum|| < ~80
    esum += e;
#pragma unroll
    for (int j = 0; j < 4; ++j) { accA[j] += e * p[j]; accB[j] += e * p[4 + j]; }
  }
  store_partials(partialA, partialE, accA, accB, esum, c, rch, t, g, b);
}

// ---------------------------------------------------------------------------
// redv: per (c,b) reduce NRCH chunk-partials (fragment-order via idx
// permutation) -> v = squash(s/esum). mode: 0 vsum=v, 1 vsum+=v, 2 out=v.
// grid 256 x 256 threads. Proven R9-R11.
// ---------------------------------------------------------------------------
__global__ __launch_bounds__(256) void caps_redv_kernel(
    const float* __restrict__ partialA, const float* __restrict__ partialE,
    float* __restrict__ vsum, float* __restrict__ out, int mode)
{
  const int cb = (int)blockIdx.x;
  const int c2 = cb >> 7, b2 = cb & 127;
  const int t  = (int)threadIdx.x;
  const int o = t & 31, jg = t >> 5;          // 8 j-groups
  const int wv2 = b2 >> 4, m2 = b2 & 15;
  const int half = o >> 4, oo = o & 15, g2 = oo >> 2, j2 = oo & 3;
  const size_t idx = (size_t)(wv2 * 64 + g2 * 16 + m2) * 8 + half * 4 + j2;

  __shared__ float red[8][33];
  __shared__ float rede[8];

  float s = 0.f;
#pragma unroll 4
  for (int k = 0; k < NRCH / 8; ++k) {
    const int j = jg + k * 8;
    s += partialA[((size_t)(c2 * NRCH + j)) * 4096 + idx];
  }
  red[jg][o] = s;
  __syncthreads();

  if (t < 8) {
    float e = 0.f;
#pragma unroll 4
    for (int k = 0; k < NRCH / 8; ++k)
      e += partialE[((size_t)(c2 * NRCH + t + k * 8)) * CB + b2];
    rede[t] = e;
  }
  __syncthreads();

  if (t < 32) {
    float sv = 0.f, es = 0.f;
#pragma unroll
    for (int jj = 0; jj < 8; ++jj) { sv += red[jj][t]; es += rede[jj]; }
    float sm = sv / es;
    float sn = sm * sm;
#pragma unroll
    for (int sh = 1; sh < 32; sh <<= 1) sn += __shfl_xor(sn, sh);
    float fac = sn / ((1.f + sn + EPSF) * sqrtf(sn + EPSF));
    float vv = sm * fac;
    if (mode == 2)      out[cb * COUT + t]  = vv;
    else if (mode == 1) vsum[cb * COUT + t] += vv;
    else                vsum[cb * COUT + t] = vv;
  }
}

extern "C" void kernel_launch(void* const* d_in, const int* in_sizes, int n_in,
                              void* d_out, int out_size, void* d_ws, size_t ws_size,
                              hipStream_t stream) {
  const float* x = (const float*)d_in[0];
  const float* w = (const float*)d_in[1];
  float* out = (float*)d_out;

  char* p = (char*)d_ws;
  h8* priors16 = (h8*)p;                           // 512*16*512*16B = 67,108,864 B
  p += (size_t)CCAP * NRCH * RC * 512 * sizeof(h8);
  float* vsum = (float*)p;                         // 32,768 B
  p += (size_t)CCAP * CB * COUT * sizeof(float);
  float* partialA = (float*)p;                     // 8,388,608 B
  p += (size_t)CCAP * NRCH * 4096 * sizeof(float);
  float* partialE = (float*)p;                     // 262,144 B
  // total 75,792,384 B — within proven workspace

  caps_pass0_kernel<<<dim3(CCAP * NRCH), 512, 0, stream>>>(
      x, w, priors16, partialA, partialE);
  caps_redv_kernel<<<dim3(CCAP * CB), 256, 0, stream>>>(
      partialA, partialE, vsum, out, 0);
  caps_passN_kernel<<<dim3(CCAP * NRCH), 512, 0, stream>>>(
      priors16, vsum, partialA, partialE);
  caps_redv_kernel<<<dim3(CCAP * CB), 256, 0, stream>>>(
      partialA, partialE, vsum, out, 1);
  caps_passN_kernel<<<dim3(CCAP * NRCH), 512, 0, stream>>>(
      priors16, vsum, partialA, partialE);
  caps_redv_kernel<<<dim3(CCAP * CB), 256, 0, stream>>>(
      partialA, partialE, vsum, out, 2);
}

// Round 13
// 78.775 us; speedup vs baseline: 1.0119x; 1.0119x over previous
//
#include <hip/hip_runtime.h>
#include <math.h>

// CapsuleLayer dynamic routing, MI355X — R13: prepack W once, 3 LDS-free
// MFMA passes + proven reductions.
// B=128, R=4096, IN=16, OUT=32, C=2, 3 routing iterations.
//
// Evidence trail: R9 coop == 6-dispatch (launch gaps small); R12 showed
// materializing 67 MB priors loses ~8 us; R7's 20.7us/pass is ~half W
// stage+pack machinery (5 barriers, 32KB LDS -> 16 waves/CU). R13 removes
// ALL LDS from the passes: W is packed to fragment order ONCE in global
// (wp, 8.4 MB, h8-interleaved so lane L reads one 16B record per r), and
// passes read frags directly (1 KB/wave contiguous, L3-resident). 0 LDS,
// 0 barriers, ~70 VGPR -> ~28 waves/CU.
// Math (proven R5+): logits linear in running v-sum; it0 softmax uniform
// (e=1). k-slot safety (HW-verified R6+): both mfma operands put
// i=4*(L>>4)+j in elements 0..3, zeros 4..7. C/D layout (m89-verified):
// col=lane&15, row=4g+reg. f16 precision proven (absmax 0.0039 < 0.0124).
#define CB    128
#define CR    4096
#define CIN   16
#define COUT  32
#define CCAP  2
#define RC    16            // r rows per chunk
#define NRCH  (CR / RC)     // 256 chunks per c
#define EPSF  1e-12f

typedef _Float16 h8  __attribute__((ext_vector_type(8)));
typedef float    f4  __attribute__((ext_vector_type(4)));

// ---------------------------------------------------------------------------
// prepack: W f32 -> wp h8 fragment-interleaved:
//   wp[(c*CR + r)*64 + L] = { W[c][r][4g+j][m] (j=0..3),
//                             W[c][r][4g+j][16+m] (j=0..3) }   g=L>>4, m=L&15
// grid = C*1024 blocks (4 W-rows each) x 256 threads.
// ---------------------------------------------------------------------------
__global__ __launch_bounds__(256) void caps_prepack_kernel(
    const float* __restrict__ w, h8* __restrict__ wp)
{
  const int blk = (int)blockIdx.x;
  const int c   = blk >> 10;
  const int r0  = (blk & 1023) * 4;
  const int t   = (int)threadIdx.x;

  __shared__ __align__(16) float Wl[4 * 512];   // 8 KB
  {
    const float4* src = (const float4*)(w + ((size_t)c * CR + r0) * 512);
    ((float4*)Wl)[t]       = src[t];
    ((float4*)Wl)[t + 256] = src[t + 256];
  }
  __syncthreads();

  const int rr = t >> 6;        // 0..3
  const int L  = t & 63;
  const int g  = L >> 4, m = L & 15;
  h8 v;
#pragma unroll
  for (int j = 0; j < 4; ++j) {
    v[j]     = (_Float16)Wl[rr * 512 + (4 * g + j) * 32 + m];
    v[4 + j] = (_Float16)Wl[rr * 512 + (4 * g + j) * 32 + 16 + m];
  }
  wp[((size_t)c * CR + r0 + rr) * 64 + L] = v;
}

// direct fragment-order partial stores (coalesced, no barriers). Proven.
__device__ __forceinline__ void store_partials(float* __restrict__ partialA,
                                               float* __restrict__ partialE,
                                               const float* accA, const float* accB,
                                               float esum, int c, int rch,
                                               int t, int g, int b)
{
  float4 a4 = {accA[0], accA[1], accA[2], accA[3]};
  float4 b4 = {accB[0], accB[1], accB[2], accB[3]};
  float* dst = partialA + ((size_t)(c * NRCH + rch)) * 4096 + (size_t)t * 8;
  *(float4*)dst = a4;
  *(float4*)(dst + 4) = b4;
  if (g == 0) partialE[((size_t)(c * NRCH + rch)) * CB + b] = esum;
}

// ---------------------------------------------------------------------------
// pass: grid = C*NRCH = 512 blocks x 512 threads. ZERO LDS, zero barriers.
// Per r: x-gather float4 + one wp h8 read -> 2 mfma -> P[o][b] frags;
// d = P.v (8 FMA + 2 shfl_xor); e = exp(d) [e=1 on uniform]; acc += e*P.
// ---------------------------------------------------------------------------
__global__ __launch_bounds__(512) void caps_pass_kernel(
    const float* __restrict__ x, const h8* __restrict__ wp,
    const float* __restrict__ vsum,
    float* __restrict__ partialA, float* __restrict__ partialE,
    int uniform)
{
  const int blk = (int)blockIdx.x;
  const int c = blk >> 8, rch = blk & 255;
  const int r0 = rch * RC;
  const int t = (int)threadIdx.x;
  const int wv = t >> 6, L = t & 63, g = L >> 4, m = L & 15;
  const int b  = wv * 16 + m;

  const h8* wrow = wp + ((size_t)c * CR + r0) * 64 + L;
  const float* xrow = x + ((size_t)b * CR + r0) * CIN + 4 * g;

  float4 vA = {0.f, 0.f, 0.f, 0.f}, vB = {0.f, 0.f, 0.f, 0.f};
  if (!uniform) {
    const float* vb = vsum + ((size_t)c * CB + b) * COUT;
    vA = *(const float4*)(vb + 4 * g);
    vB = *(const float4*)(vb + 16 + 4 * g);
  }

  float accA[4] = {0.f, 0.f, 0.f, 0.f};
  float accB[4] = {0.f, 0.f, 0.f, 0.f};
  float esum = 0.f;

#pragma unroll 4
  for (int ri = 0; ri < RC; ++ri) {
    // B-frag: x[b][r][4g..4g+3] -> elements 0..3, zeros 4..7
    float4 xf = *(const float4*)(xrow + ri * CIN);
    h8 bx = {(_Float16)xf.x, (_Float16)xf.y, (_Float16)xf.z, (_Float16)xf.w,
             (_Float16)0.f, (_Float16)0.f, (_Float16)0.f, (_Float16)0.f};
    // A-frags: one 16B global read (1 KB/wave contiguous, L3-resident)
    h8 wf = wrow[ri * 64];
    h8 aA = {wf[0], wf[1], wf[2], wf[3],
             (_Float16)0.f, (_Float16)0.f, (_Float16)0.f, (_Float16)0.f};
    h8 aB = {wf[4], wf[5], wf[6], wf[7],
             (_Float16)0.f, (_Float16)0.f, (_Float16)0.f, (_Float16)0.f};
    f4 z = {0.f, 0.f, 0.f, 0.f};
    f4 pA = __builtin_amdgcn_mfma_f32_16x16x32_f16(aA, bx, z, 0, 0, 0);
    f4 pB = __builtin_amdgcn_mfma_f32_16x16x32_f16(aB, bx, z, 0, 0, 0);

    float e = 1.f;                 // it0: softmax over zero logits
    if (!uniform) {
      float d = pA[0] * vA.x + pA[1] * vA.y + pA[2] * vA.z + pA[3] * vA.w
              + pB[0] * vB.x + pB[1] * vB.y + pB[2] * vB.z + pB[3] * vB.w;
      d += __shfl_xor(d, 16);
      d += __shfl_xor(d, 32);
      e = __expf(d);               // safe: |d| <= ||p_row|| * ||vsum|| < ~80
    }
    esum += e;
#pragma unroll
    for (int j = 0; j < 4; ++j) { accA[j] += e * pA[j]; accB[j] += e * pB[j]; }
  }
  store_partials(partialA, partialE, accA, accB, esum, c, rch, t, g, b);
}

// ---------------------------------------------------------------------------
// redv: per (c,b) reduce NRCH chunk-partials (fragment-order via idx
// permutation) -> v = squash(s/esum). mode: 0 vsum=v, 1 vsum+=v, 2 out=v.
// grid 256 x 256 threads. Proven R9-R12.
// ---------------------------------------------------------------------------
__global__ __launch_bounds__(256) void caps_redv_kernel(
    const float* __restrict__ partialA, const float* __restrict__ partialE,
    float* __restrict__ vsum, float* __restrict__ out, int mode)
{
  const int cb = (int)blockIdx.x;
  const int c2 = cb >> 7, b2 = cb & 127;
  const int t  = (int)threadIdx.x;
  const int o = t & 31, jg = t >> 5;          // 8 j-groups
  const int wv2 = b2 >> 4, m2 = b2 & 15;
  const int half = o >> 4, oo = o & 15, g2 = oo >> 2, j2 = oo & 3;
  const size_t idx = (size_t)(wv2 * 64 + g2 * 16 + m2) * 8 + half * 4 + j2;

  __shared__ float red[8][33];
  __shared__ float rede[8];

  float s = 0.f;
#pragma unroll 4
  for (int k = 0; k < NRCH / 8; ++k) {
    const int j = jg + k * 8;
    s += partialA[((size_t)(c2 * NRCH + j)) * 4096 + idx];
  }
  red[jg][o] = s;
  __syncthreads();

  if (t < 8) {
    float e = 0.f;
#pragma unroll 4
    for (int k = 0; k < NRCH / 8; ++k)
      e += partialE[((size_t)(c2 * NRCH + t + k * 8)) * CB + b2];
    rede[t] = e;
  }
  __syncthreads();

  if (t < 32) {
    float sv = 0.f, es = 0.f;
#pragma unroll
    for (int jj = 0; jj < 8; ++jj) { sv += red[jj][t]; es += rede[jj]; }
    float sm = sv / es;
    float sn = sm * sm;
#pragma unroll
    for (int sh = 1; sh < 32; sh <<= 1) sn += __shfl_xor(sn, sh);
    float fac = sn / ((1.f + sn + EPSF) * sqrtf(sn + EPSF));
    float vv = sm * fac;
    if (mode == 2)      out[cb * COUT + t]  = vv;
    else if (mode == 1) vsum[cb * COUT + t] += vv;
    else                vsum[cb * COUT + t] = vv;
  }
}

extern "C" void kernel_launch(void* const* d_in, const int* in_sizes, int n_in,
                              void* d_out, int out_size, void* d_ws, size_t ws_size,
                              hipStream_t stream) {
  const float* x = (const float*)d_in[0];
  const float* w = (const float*)d_in[1];
  float* out = (float*)d_out;

  char* p = (char*)d_ws;
  h8* wp = (h8*)p;                                 // 2*4096*64*16B = 8,388,608 B
  p += (size_t)CCAP * CR * 64 * sizeof(h8);
  float* vsum = (float*)p;                         // 32,768 B
  p += (size_t)CCAP * CB * COUT * sizeof(float);
  float* partialA = (float*)p;                     // 8,388,608 B
  p += (size_t)CCAP * NRCH * 4096 * sizeof(float);
  float* partialE = (float*)p;                     // 262,144 B
  // total ~17 MB

  caps_prepack_kernel<<<dim3(CCAP * 1024), 256, 0, stream>>>(w, wp);
  caps_pass_kernel<<<dim3(CCAP * NRCH), 512, 0, stream>>>(
      x, wp, vsum, partialA, partialE, 1);
  caps_redv_kernel<<<dim3(CCAP * CB), 256, 0, stream>>>(
      partialA, partialE, vsum, out, 0);
  caps_pass_kernel<<<dim3(CCAP * NRCH), 512, 0, stream>>>(
      x, wp, vsum, partialA, partialE, 0);
  caps_redv_kernel<<<dim3(CCAP * CB), 256, 0, stream>>>(
      partialA, partialE, vsum, out, 1);
  caps_pass_kernel<<<dim3(CCAP * NRCH), 512, 0, stream>>>(
      x, wp, vsum, partialA, partialE, 0);
  caps_redv_kernel<<<dim3(CCAP * CB), 256, 0, stream>>>(
      partialA, partialE, vsum, out, 2);
}